// Round 8
// baseline (251.418 us; speedup 1.0000x reference)
//
#include <hip/hip_runtime.h>
#include <hip/hip_bf16.h>

typedef __attribute__((ext_vector_type(8))) short short8;
typedef __attribute__((ext_vector_type(4))) float f32x4;
typedef unsigned short ush;

#define MFMA_B16(a, b, c) __builtin_amdgcn_mfma_f32_16x16x32_bf16((a), (b), (c), 0, 0, 0)

__device__ __forceinline__ float bf2f(ush u) {
    union { unsigned int i; float f; } v; v.i = ((unsigned int)u) << 16; return v.f;
}
__device__ __forceinline__ ush f2bf(float f) {
    union { float f; unsigned int i; } v; v.f = f;
    unsigned int r = v.i + 0x7fffu + ((v.i >> 16) & 1u);
    return (ush)(r >> 16);
}
// fast HW transcendentals. Gate scales folded into weights at convert time:
// z/r pre-acts pre-multiplied by -log2(e), gru2 candidate by 2*log2(e).
__device__ __forceinline__ float rcp_f(float x) { return __builtin_amdgcn_rcpf(x); }
__device__ __forceinline__ float sigm_pre(float x) {      // x = -log2(e)*(...)
    return rcp_f(1.0f + __builtin_amdgcn_exp2f(x));
}

// LDS-only barrier: cross-wave traffic in the GRU loops is LDS-only (Ah/Ax/
// Pbuf), so lgkmcnt(0)+s_barrier suffices; global loads/stores stay in flight.
__device__ __forceinline__ void lds_barrier() {
    asm volatile("s_waitcnt lgkmcnt(0)" ::: "memory");
    __builtin_amdgcn_s_barrier();
    asm volatile("" ::: "memory");
}

// probe 256 shorts: bf16 vs fp32 discrimination (deterministic per call)
__device__ __forceinline__ bool probe_bf16(const ush* p, int tid, int* s_cnt) {
    if (tid == 0) *s_cnt = 0;
    __syncthreads();
    ush s = p[tid & 255];
    int e = (s >> 7) & 0xFF;
    if (tid < 256 && e >= 117 && e <= 137) atomicAdd(s_cnt, 1);
    __syncthreads();
    return *s_cnt >= 200;
}

// ---------------------------------------------------------------------------
// Convert 20 weight/bias tensors to bf16 arena with gate scale folding.
// ---------------------------------------------------------------------------
struct WArgs {
    const void* src[20];
    int off[21];
};

__global__ __launch_bounds__(256)
void convert_w(WArgs a, ush* __restrict__ arena, const ush* __restrict__ probe)
{
    __shared__ int cnt;
    const bool bf = probe_bf16(probe, threadIdx.x, &cnt);
    const int total = a.off[20];
    for (int i = blockIdx.x * 256 + threadIdx.x; i < total; i += gridDim.x * 256) {
        int t = 0;
        while (t < 19 && i >= a.off[t + 1]) ++t;
        const int local = i - a.off[t];
        float v = bf ? bf2f(((const ush*)a.src[t])[local])
                     : ((const float*)a.src[t])[local];
        if (t < 16) {
            const int col = local % 192;
            if (col < 128) v *= -1.4426950408889634f;
            else if (t >= 8) v *= 2.885390081777927f;
        }
        arena[i] = f2bf(v);
    }
}

// ---------------------------------------------------------------------------
// Layer 1: bidirectional GRU(64), relu candidate. 16 rows/block, 4 waves x 16
// units; h via double-buffered LDS (rows padded 72->76, conflict-free) +
// LDS-only barrier; x staged in LDS (padded 40->44), depth-2 raw-bit prefetch.
// Measured ~35us/launch. grid (bchunk/16, 2), block 256.
// ---------------------------------------------------------------------------
__global__ __launch_bounds__(256, 1)
void gru1_kernel(const void* __restrict__ X, const void* __restrict__ h0f,
                 const void* __restrict__ h0b, int cb, int bchunk,
                 const ush* __restrict__ Wf, const ush* __restrict__ Uf,
                 const ush* __restrict__ bif, const ush* __restrict__ brf,
                 const ush* __restrict__ Wb, const ush* __restrict__ Ub,
                 const ush* __restrict__ bib, const ush* __restrict__ brb,
                 ush* __restrict__ seq)
{
    const int tid  = threadIdx.x;
    const int lane = tid & 63;
    const int wv   = tid >> 6;
    const int q    = lane >> 4;
    const int ln   = lane & 15;
    const int dir  = blockIdx.y;
    const int lb0  = blockIdx.x * 16;
    const int gb0  = cb + lb0;
    const int u    = wv * 16 + ln;

    const ush* W  = dir ? Wb  : Wf;
    const ush* U  = dir ? Ub  : Uf;
    const ush* bi = dir ? bib : bif;
    const ush* br = dir ? brb : brf;
    const void* h0 = dir ? h0b : h0f;

    __shared__ __align__(16) ush Ah[2][16][76];   // padded: 38-word row stride
    __shared__ __align__(16) ush Ax[2][16][44];   // padded: 22-word row stride
    __shared__ int s_cnt;

    const bool xbf = probe_bf16((const ush*)X, tid, &s_cnt);

    {
        ush* p = &Ax[0][0][0];
        for (int i = tid; i < 2 * 16 * 44; i += 256) p[i] = 0;
    }
    __syncthreads();

    {
        const int tx0 = dir ? 71 : 0;
        if (tid < 144) {
            int r = tid / 9, k = tid - 9 * r;
            size_t idx = ((size_t)(gb0 + r) * 72 + tx0) * 9 + k;
            ush hv, lv;
            if (xbf) { hv = ((const ush*)X)[idx]; lv = 0; }
            else { float v = ((const float*)X)[idx]; hv = f2bf(v); lv = f2bf(v - bf2f(hv)); }
            Ax[0][r][2 * k]     = hv;
            Ax[0][r][2 * k + 1] = lv;
        }
    }

    short8 bU[3][2];
    short8 bW[3];
#pragma unroll
    for (int g = 0; g < 3; ++g) {
        const int col = g * 64 + u;
#pragma unroll
        for (int ks = 0; ks < 2; ++ks) {
            short8 f;
#pragma unroll
            for (int j = 0; j < 8; ++j) {
                int kp = ks * 32 + q * 8 + j;
                f[j] = (short)U[(size_t)kp * 192 + col];
            }
            bU[g][ks] = f;
        }
        short8 fw;
#pragma unroll
        for (int j = 0; j < 8; ++j) {
            int kp = q * 8 + j;
            fw[j] = (kp < 18) ? (short)W[(size_t)(kp >> 1) * 192 + col] : (short)0;
        }
        bW[g] = fw;
    }

    const float bz  = bf2f(bi[u])       + bf2f(br[u]);        // pre-scaled
    const float brg = bf2f(bi[64 + u])  + bf2f(br[64 + u]);   // pre-scaled
    const float bih = bf2f(bi[128 + u]);                      // unscaled (relu)
    const float brh = bf2f(br[128 + u]);
    const f32x4 Cz  = {bz,  bz,  bz,  bz};
    const f32x4 Cr  = {brg, brg, brg, brg};
    const f32x4 Chx = {bih, bih, bih, bih};
    const f32x4 Chr = {brh, brh, brh, brh};

    float hreg[4];
#pragma unroll
    for (int i = 0; i < 4; ++i) {
        int m = q * 4 + i;
        size_t idx = (size_t)(gb0 + m) * 64 + u;
        float hv = xbf ? bf2f(((const ush*)h0)[idx])
                       : ((const float*)h0)[idx];
        hreg[i] = hv;
        Ah[0][m][u] = f2bf(hv);
    }

    const int r2 = tid >> 3, c2 = tid & 7;
    const int r0x = tid / 9, k0x = tid - 9 * r0x;

    // depth-2 x pipeline, raw bits: craw holds x(t+1); conversion at the
    // LDS-write point one step later.
    unsigned int craw = 0;
    if (tid < 144) {
        const int tx = dir ? 70 : 1;
        size_t idx = ((size_t)(gb0 + r0x) * 72 + tx) * 9 + k0x;
        craw = xbf ? (unsigned int)((const ush*)X)[idx]
                   : ((const unsigned int*)X)[idx];
    }
    __syncthreads();

#pragma unroll 2
    for (int t = 0; t < 72; ++t) {
        const int cur = t & 1, nb = cur ^ 1;

        unsigned int fraw = 0;
        if (t < 70 && tid < 144) {
            const int tx = dir ? (69 - t) : (t + 2);
            size_t idx = ((size_t)(gb0 + r0x) * 72 + tx) * 9 + k0x;
            fraw = xbf ? (unsigned int)((const ush*)X)[idx]
                       : ((const unsigned int*)X)[idx];
        }

        if (t > 0 && tid < 128) {
            const int tw = dir ? (71 - (t - 1)) : (t - 1);
            int4 v = *(const int4*)&Ah[cur][r2][c2 * 8];
            *(int4*)(seq + ((size_t)tw * bchunk + lb0 + r2) * 128 + dir * 64 + c2 * 8) = v;
        }

        const ush* ap = &Ah[cur][ln][0];
        short8 a0 = *(const short8*)(ap + q * 8);
        short8 a1 = *(const short8*)(ap + 32 + q * 8);
        short8 ax = *(const short8*)(&Ax[cur][ln][q * 8]);
        f32x4 az  = MFMA_B16(ax, bW[0], Cz);
        az        = MFMA_B16(a0, bU[0][0], az);
        az        = MFMA_B16(a1, bU[0][1], az);
        f32x4 ar  = MFMA_B16(ax, bW[1], Cr);
        ar        = MFMA_B16(a0, bU[1][0], ar);
        ar        = MFMA_B16(a1, bU[1][1], ar);
        f32x4 ahx = MFMA_B16(ax, bW[2], Chx);
        f32x4 ahr = MFMA_B16(a0, bU[2][0], Chr);
        ahr       = MFMA_B16(a1, bU[2][1], ahr);

#pragma unroll
        for (int i = 0; i < 4; ++i) {
            const int m = q * 4 + i;
            float z = sigm_pre(az[i]);
            float r = sigm_pre(ar[i]);
            float pre = ahx[i] + r * ahr[i];
            float hh = fmaxf(pre, 0.0f);
            float hn = hh + z * (hreg[i] - hh);
            hreg[i] = hn;
            Ah[nb][m][u] = f2bf(hn);
        }

        if (t < 71 && tid < 144) {
            ush hv, lv;
            if (xbf) { hv = (ush)craw; lv = 0; }
            else {
                float v = __uint_as_float(craw);
                hv = f2bf(v); lv = f2bf(v - bf2f(hv));
            }
            Ax[nb][r0x][2 * k0x]     = hv;
            Ax[nb][r0x][2 * k0x + 1] = lv;
        }
        craw = fraw;
        lds_barrier();
    }

    if (tid < 128) {
        const int tw = dir ? 0 : 71;
        int4 v = *(const int4*)&Ah[0][r2][c2 * 8];
        *(int4*)(seq + ((size_t)tw * bchunk + lb0 + r2) * 128 + dir * 64 + c2 * 8) = v;
    }
}

// ---------------------------------------------------------------------------
// Layer 2 (R4-verified, inferred ~33.5us): bidirectional GRU(64), tanh
// (pre-scaled). Producer/consumer wave PAIR per 16 batch rows: wave0 computes
// x-projections P(t+1) for all 64 units (bV in regs, seq prefetch depth 3)
// into double-buffered LDS; wave1 does recurrence + gates only (h
// wave-private). One 2-wave LDS barrier per step; the h-chain never crosses
// it. grid (bchunk/16, 2), block 128.
// ---------------------------------------------------------------------------
#define PROD_STEP(FA, BUFI, T)                                                 \
    do {                                                                       \
        if ((T) < 71) {                                                        \
            _Pragma("unroll") for (int g = 0; g < 3; ++g) {                    \
                _Pragma("unroll") for (int n = 0; n < 4; ++n) {                \
                    f32x4 acc = MFMA_B16(FA[0], bV[g][0][n], Cg[g][n]);        \
                    acc = MFMA_B16(FA[1], bV[g][1][n], acc);                   \
                    acc = MFMA_B16(FA[2], bV[g][2][n], acc);                   \
                    acc = MFMA_B16(FA[3], bV[g][3][n], acc);                   \
                    *(f32x4*)&Pbuf[BUFI][g][n][poff] = acc;                    \
                }                                                              \
            }                                                                  \
        }                                                                      \
        if ((T) < 69) {                                                        \
            const ush* sp = sptr0 + (long long)((T) + 3) * tstride;            \
            FA[0] = *(const short8*)sp;                                        \
            FA[1] = *(const short8*)(sp + 32);                                 \
            FA[2] = *(const short8*)(sp + 64);                                 \
            FA[3] = *(const short8*)(sp + 96);                                 \
        }                                                                      \
    } while (0)

#define CONS_STEP(BUFI, T)                                                     \
    do {                                                                       \
        f32x4 Pz[4], Pr[4], Pc[4];                                             \
        _Pragma("unroll") for (int n = 0; n < 4; ++n) {                        \
            Pz[n] = *(const f32x4*)&Pbuf[BUFI][0][n][poff];                    \
            Pr[n] = *(const f32x4*)&Pbuf[BUFI][1][n][poff];                    \
            Pc[n] = *(const f32x4*)&Pbuf[BUFI][2][n][poff];                    \
        }                                                                      \
        short8 a0 = *(const short8*)&Ah[ln][q * 8];                            \
        short8 a1 = *(const short8*)&Ah[ln][32 + q * 8];                       \
        f32x4 az[4], ar[4], ahr[4];                                            \
        _Pragma("unroll") for (int n = 0; n < 4; ++n) {                        \
            az[n]  = MFMA_B16(a0, bU[0][0][n], Pz[n]);                         \
            az[n]  = MFMA_B16(a1, bU[0][1][n], az[n]);                         \
            ar[n]  = MFMA_B16(a0, bU[1][0][n], Pr[n]);                         \
            ar[n]  = MFMA_B16(a1, bU[1][1][n], ar[n]);                         \
            ahr[n] = MFMA_B16(a0, bU[2][0][n], Chr[n]);                        \
            ahr[n] = MFMA_B16(a1, bU[2][1][n], ahr[n]);                        \
        }                                                                      \
        _Pragma("unroll") for (int n = 0; n < 4; ++n)                          \
            _Pragma("unroll") for (int i = 0; i < 4; ++i) {                    \
                float z = sigm_pre(az[n][i]);                                  \
                float r = sigm_pre(ar[n][i]);                                  \
                float pre = Pc[n][i] + r * ahr[n][i];                          \
                float e = __builtin_amdgcn_exp2f(pre);  /* pre-scaled */       \
                float hh = 1.0f - 2.0f * rcp_f(e + 1.0f);                      \
                float hn = hh + z * (hreg[n][i] - hh);                         \
                hreg[n][i] = hn;                                               \
                Ah[q * 4 + i][n * 16 + ln] = f2bf(hn);                         \
            }                                                                  \
    } while (0)

__global__ __launch_bounds__(128, 1)
void gru2_kernel(const ush* __restrict__ seq, int cb, int bchunk,
                 const ush* __restrict__ W2f, const ush* __restrict__ U2f,
                 const ush* __restrict__ bi2f, const ush* __restrict__ br2f,
                 const ush* __restrict__ W2b, const ush* __restrict__ U2b,
                 const ush* __restrict__ bi2b, const ush* __restrict__ br2b,
                 float* __restrict__ feat)
{
    const int tid = threadIdx.x;
    const int wv = tid >> 6, lane = tid & 63, q = lane >> 4, ln = lane & 15;
    const int dir = blockIdx.y, lb0 = blockIdx.x * 16, gb0 = cb + lb0;

    const ush* W  = dir ? W2b  : W2f;
    const ush* U  = dir ? U2b  : U2f;
    const ush* bi = dir ? bi2b : bi2f;
    const ush* br = dir ? br2b : br2f;

    // Pbuf: per (buf,gate,tile): 8 groups of (8 lanes x 16B) + 16B pad
    __shared__ __align__(16) float Pbuf[2][3][4][288];
    __shared__ __align__(16) ush Ah[16][72];

    const int poff = (lane >> 3) * 36 + (lane & 7) * 4;

    if (wv == 0) {
        // ---------------- producer ----------------
        short8 bV[3][4][4];
#pragma unroll
        for (int g = 0; g < 3; ++g)
#pragma unroll
            for (int n = 0; n < 4; ++n) {
                const int col = g * 64 + n * 16 + ln;
#pragma unroll
                for (int ks = 0; ks < 4; ++ks) {
                    short8 f;
#pragma unroll
                    for (int j = 0; j < 8; ++j) {
                        int kp = ks * 32 + q * 8 + j;
                        f[j] = (short)W[(size_t)kp * 192 + col];
                    }
                    bV[g][ks][n] = f;
                }
            }
        f32x4 Cg[3][4];
#pragma unroll
        for (int n = 0; n < 4; ++n) {
            const int u2 = n * 16 + ln;
            const float bz  = bf2f(bi[u2]) + bf2f(br[u2]);
            const float brg = bf2f(bi[64 + u2]) + bf2f(br[64 + u2]);
            const float bih = bf2f(bi[128 + u2]);
            Cg[0][n] = (f32x4){bz, bz, bz, bz};
            Cg[1][n] = (f32x4){brg, brg, brg, brg};
            Cg[2][n] = (f32x4){bih, bih, bih, bih};
        }

        const long long tstride = (long long)bchunk * 128 * (dir ? -1 : 1);
        const ush* sptr0 = seq + (size_t)(lb0 + ln) * 128 + q * 8
                         + (dir ? 71ll * bchunk * 128 : 0);

        // P(0) -> buf0
        {
            const ush* sp = sptr0;
            short8 s0 = *(const short8*)sp;
            short8 s1 = *(const short8*)(sp + 32);
            short8 s2 = *(const short8*)(sp + 64);
            short8 s3 = *(const short8*)(sp + 96);
#pragma unroll
            for (int g = 0; g < 3; ++g)
#pragma unroll
                for (int n = 0; n < 4; ++n) {
                    f32x4 acc = MFMA_B16(s0, bV[g][0][n], Cg[g][n]);
                    acc = MFMA_B16(s1, bV[g][1][n], acc);
                    acc = MFMA_B16(s2, bV[g][2][n], acc);
                    acc = MFMA_B16(s3, bV[g][3][n], acc);
                    *(f32x4*)&Pbuf[0][g][n][poff] = acc;
                }
        }
        short8 F0[4], F1[4];
        {
            const ush* sp = sptr0 + tstride;
            F0[0] = *(const short8*)sp;        F0[1] = *(const short8*)(sp + 32);
            F0[2] = *(const short8*)(sp + 64); F0[3] = *(const short8*)(sp + 96);
        }
        {
            const ush* sp = sptr0 + 2 * tstride;
            F1[0] = *(const short8*)sp;        F1[1] = *(const short8*)(sp + 32);
            F1[2] = *(const short8*)(sp + 64); F1[3] = *(const short8*)(sp + 96);
        }
        lds_barrier();

        for (int t = 0; t < 72; t += 2) {
            PROD_STEP(F0, 1, t);
            lds_barrier();
            PROD_STEP(F1, 0, t + 1);
            lds_barrier();
        }
    } else {
        // ---------------- consumer ----------------
        short8 bU[3][2][4];
#pragma unroll
        for (int g = 0; g < 3; ++g)
#pragma unroll
            for (int n = 0; n < 4; ++n) {
                const int col = g * 64 + n * 16 + ln;
#pragma unroll
                for (int ks = 0; ks < 2; ++ks) {
                    short8 f;
#pragma unroll
                    for (int j = 0; j < 8; ++j) {
                        int kp = ks * 32 + q * 8 + j;
                        f[j] = (short)U[(size_t)kp * 192 + col];
                    }
                    bU[g][ks][n] = f;
                }
            }
        f32x4 Chr[4];
#pragma unroll
        for (int n = 0; n < 4; ++n) {
            const float brh = bf2f(br[128 + n * 16 + ln]);
            Chr[n] = (f32x4){brh, brh, brh, brh};
        }

        // h(0) = 0
        for (int i = lane; i < 16 * 72; i += 64) (&Ah[0][0])[i] = 0;
        float hreg[4][4];
#pragma unroll
        for (int n = 0; n < 4; ++n)
#pragma unroll
            for (int i = 0; i < 4; ++i) hreg[n][i] = 0.0f;
        lds_barrier();

        for (int t = 0; t < 72; t += 2) {
            CONS_STEP(0, t);
            lds_barrier();
            CONS_STEP(1, t + 1);
            lds_barrier();
        }

#pragma unroll
        for (int n = 0; n < 4; ++n)
#pragma unroll
            for (int i = 0; i < 4; ++i)
                feat[(size_t)(gb0 + q * 4 + i) * 128 + dir * 64 + n * 16 + ln] = hreg[n][i];
    }
}

// ---------------------------------------------------------------------------
__global__ __launch_bounds__(256, 1)
void head_kernel(const float* __restrict__ feat,
                 const ush* __restrict__ dW, const ush* __restrict__ db,
                 const ush* __restrict__ oW, const ush* __restrict__ ob,
                 float* __restrict__ out)
{
    const int tid = threadIdx.x;
    const int b0  = blockIdx.x * 16;

    __shared__ __align__(16) ush Wl[128][136];
    __shared__ __align__(16) float fs[16][128];
    __shared__ __align__(16) float hs[16][136];
    __shared__ __align__(16) float ls[16][32];

    for (int i = tid; i < 2048; i += 256) {
        const int k = i >> 4;
        const int c = (i & 15) * 8;
        *(int4*)&Wl[k][c] = *(const int4*)(dW + (size_t)k * 128 + c);
    }
    {
        const float4* src = (const float4*)(feat + (size_t)b0 * 128);
        float4* dst = (float4*)&fs[0][0];
        for (int i = tid; i < 512; i += 256) dst[i] = src[i];
    }
    __syncthreads();

    {
        const int row = tid >> 4;
        const int j0  = (tid & 15) * 8;
        float acc[8];
#pragma unroll
        for (int jj = 0; jj < 8; ++jj) acc[jj] = bf2f(db[j0 + jj]);
        for (int k = 0; k < 128; ++k) {
            float f = fs[row][k];
            short8 w = *(const short8*)&Wl[k][j0];
#pragma unroll
            for (int jj = 0; jj < 8; ++jj)
                acc[jj] += f * bf2f((ush)w[jj]);
        }
#pragma unroll
        for (int jj = 0; jj < 8; ++jj) hs[row][j0 + jj] = fmaxf(acc[jj], 0.0f);
    }
    __syncthreads();

    for (int e = tid; e < 16 * 24; e += 256) {
        const int row = e / 24, l = e - 24 * row;
        float acc = bf2f(ob[l]);
        for (int k = 0; k < 128; ++k)
            acc += hs[row][k] * bf2f(oW[(size_t)k * 24 + l]);
        ls[row][l] = acc;
    }
    __syncthreads();

    for (int e = tid; e < 16 * 24; e += 256) {
        const int row = e / 24, l = e - 24 * row;
        float mx = ls[row][0];
#pragma unroll
        for (int k = 1; k < 24; ++k) mx = fmaxf(mx, ls[row][k]);
        float s = 0.0f;
#pragma unroll
        for (int k = 0; k < 24; ++k) s += __expf(ls[row][k] - mx);
        float v = __expf(ls[row][l] - mx) * rcp_f(s);
        out[(size_t)(b0 + row) * 24 + l] = v;
    }
}

// ---------------------------------------------------------------------------
extern "C" void kernel_launch(void* const* d_in, const int* in_sizes, int n_in,
                              void* d_out, int out_size, void* d_ws, size_t ws_size,
                              hipStream_t stream) {
    (void)in_sizes; (void)n_in; (void)out_size;

    static const int wc[20] = {
        1728, 12288, 192, 192,     // d1f W,U,bi,br   (t 0..3)
        1728, 12288, 192, 192,     // d1b             (t 4..7)
        24576, 12288, 192, 192,    // d2f             (t 8..11)
        24576, 12288, 192, 192,    // d2b             (t 12..15)
        16384, 128,                // dense           (t 16,17)
        3072, 24                   // out             (t 18,19)
    };

    WArgs a;
    int off = 0;
    for (int t = 0; t < 20; ++t) {
        a.src[t] = d_in[t + 3];
        a.off[t] = off;
        off += wc[t];
    }
    a.off[20] = off;                         // 122,904 elements

    const unsigned long long arena_bytes = 245952ull;
    const unsigned long long feat_bytes  = 4096ull * 128ull * 4ull;
    const unsigned long long seq_full    = 72ull * 4096ull * 128ull * 2ull;
    const unsigned long long fixed       = arena_bytes + feat_bytes;

    int nc = 32;
    for (int c = 1; c <= 32; c *= 2) {
        if (fixed + seq_full / (unsigned long long)c <= (unsigned long long)ws_size) { nc = c; break; }
    }
    const int bchunk = 4096 / nc;

    ush* arena  = (ush*)d_ws;
    float* feat = (float*)((char*)d_ws + arena_bytes);
    ush* seq    = (ush*)((char*)d_ws + fixed);

    convert_w<<<128, 256, 0, stream>>>(a, arena, (const ush*)d_in[0]);

    const ush* d1fW = arena + a.off[0];
    const ush* d1fU = arena + a.off[1];
    const ush* d1fbi= arena + a.off[2];
    const ush* d1fbr= arena + a.off[3];
    const ush* d1bW = arena + a.off[4];
    const ush* d1bU = arena + a.off[5];
    const ush* d1bbi= arena + a.off[6];
    const ush* d1bbr= arena + a.off[7];
    const ush* d2fW = arena + a.off[8];
    const ush* d2fU = arena + a.off[9];
    const ush* d2fbi= arena + a.off[10];
    const ush* d2fbr= arena + a.off[11];
    const ush* d2bW = arena + a.off[12];
    const ush* d2bU = arena + a.off[13];
    const ush* d2bbi= arena + a.off[14];
    const ush* d2bbr= arena + a.off[15];
    const ush* dW   = arena + a.off[16];
    const ush* db   = arena + a.off[17];
    const ush* oW   = arena + a.off[18];
    const ush* ob   = arena + a.off[19];

    for (int c = 0; c < nc; ++c) {
        const int cb = c * bchunk;
        gru1_kernel<<<dim3(bchunk / 16, 2), 256, 0, stream>>>(
            d_in[0], d_in[1], d_in[2], cb, bchunk,
            d1fW, d1fU, d1fbi, d1fbr, d1bW, d1bU, d1bbi, d1bbr, seq);
        gru2_kernel<<<dim3(bchunk / 16, 2), 128, 0, stream>>>(
            seq, cb, bchunk,
            d2fW, d2fU, d2fbi, d2fbr, d2bW, d2bU, d2bbi, d2bbr, feat);
    }
    head_kernel<<<256, 256, 0, stream>>>(
        feat, dW, db, oW, ob, (float*)d_out);
}

// Round 9
// 248.676 us; speedup vs baseline: 1.0110x; 1.0110x over previous
//
#include <hip/hip_runtime.h>
#include <hip/hip_bf16.h>

typedef __attribute__((ext_vector_type(8))) short short8;
typedef __attribute__((ext_vector_type(4))) float f32x4;
typedef unsigned short ush;

#define MFMA_B16(a, b, c) __builtin_amdgcn_mfma_f32_16x16x32_bf16((a), (b), (c), 0, 0, 0)

__device__ __forceinline__ float bf2f(ush u) {
    union { unsigned int i; float f; } v; v.i = ((unsigned int)u) << 16; return v.f;
}
__device__ __forceinline__ ush f2bf(float f) {
    union { float f; unsigned int i; } v; v.f = f;
    unsigned int r = v.i + 0x7fffu + ((v.i >> 16) & 1u);
    return (ush)(r >> 16);
}
// fast HW transcendentals. Gate scales folded into weights at convert time:
// z/r pre-acts pre-multiplied by -log2(e), gru2 candidate by 2*log2(e).
__device__ __forceinline__ float rcp_f(float x) { return __builtin_amdgcn_rcpf(x); }
__device__ __forceinline__ float sigm_pre(float x) {      // x = -log2(e)*(...)
    return rcp_f(1.0f + __builtin_amdgcn_exp2f(x));
}
__device__ __forceinline__ float tanh_pre(float x) {      // x = 2*log2(e)*(...)
    return 1.0f - 2.0f * rcp_f(__builtin_amdgcn_exp2f(x) + 1.0f);
}

// LDS-only barrier: cross-wave traffic in the GRU loops is LDS-only (Ah/Ax),
// so lgkmcnt(0)+s_barrier suffices; global loads/stores stay in flight.
__device__ __forceinline__ void lds_barrier() {
    asm volatile("s_waitcnt lgkmcnt(0)" ::: "memory");
    __builtin_amdgcn_s_barrier();
    asm volatile("" ::: "memory");
}

// probe 256 shorts: bf16 vs fp32 discrimination (deterministic per call)
__device__ __forceinline__ bool probe_bf16(const ush* p, int tid, int* s_cnt) {
    if (tid == 0) *s_cnt = 0;
    __syncthreads();
    ush s = p[tid & 255];
    int e = (s >> 7) & 0xFF;
    if (tid < 256 && e >= 117 && e <= 137) atomicAdd(s_cnt, 1);
    __syncthreads();
    return *s_cnt >= 200;
}

// ---------------------------------------------------------------------------
// Convert 20 weight/bias tensors to bf16 arena with gate scale folding.
// ---------------------------------------------------------------------------
struct WArgs {
    const void* src[20];
    int off[21];
};

__global__ __launch_bounds__(256)
void convert_w(WArgs a, ush* __restrict__ arena, const ush* __restrict__ probe)
{
    __shared__ int cnt;
    const bool bf = probe_bf16(probe, threadIdx.x, &cnt);
    const int total = a.off[20];
    for (int i = blockIdx.x * 256 + threadIdx.x; i < total; i += gridDim.x * 256) {
        int t = 0;
        while (t < 19 && i >= a.off[t + 1]) ++t;
        const int local = i - a.off[t];
        float v = bf ? bf2f(((const ush*)a.src[t])[local])
                     : ((const float*)a.src[t])[local];
        if (t < 16) {
            const int col = local % 192;
            if (col < 128) v *= -1.4426950408889634f;
            else if (t >= 8) v *= 2.885390081777927f;
        }
        arena[i] = f2bf(v);
    }
}

// ---------------------------------------------------------------------------
// Layer 1: bidirectional GRU(64), relu candidate. 16 rows/block, 4 waves x 16
// units; h via double-buffered LDS (rows padded 72->76, conflict-free) +
// LDS-only barrier; x staged in LDS (padded 40->44), depth-2 raw-bit prefetch.
// setprio(1) wraps the serial chain (A-frag reads -> MFMAs -> gates -> h
// write) so co-resident blocks' waves interleave (T5). grid (bchunk/16, 2).
// ---------------------------------------------------------------------------
__global__ __launch_bounds__(256, 1)
void gru1_kernel(const void* __restrict__ X, const void* __restrict__ h0f,
                 const void* __restrict__ h0b, int cb, int bchunk,
                 const ush* __restrict__ Wf, const ush* __restrict__ Uf,
                 const ush* __restrict__ bif, const ush* __restrict__ brf,
                 const ush* __restrict__ Wb, const ush* __restrict__ Ub,
                 const ush* __restrict__ bib, const ush* __restrict__ brb,
                 ush* __restrict__ seq)
{
    const int tid  = threadIdx.x;
    const int lane = tid & 63;
    const int wv   = tid >> 6;
    const int q    = lane >> 4;
    const int ln   = lane & 15;
    const int dir  = blockIdx.y;
    const int lb0  = blockIdx.x * 16;
    const int gb0  = cb + lb0;
    const int u    = wv * 16 + ln;

    const ush* W  = dir ? Wb  : Wf;
    const ush* U  = dir ? Ub  : Uf;
    const ush* bi = dir ? bib : bif;
    const ush* br = dir ? brb : brf;
    const void* h0 = dir ? h0b : h0f;

    __shared__ __align__(16) ush Ah[2][16][76];   // padded: 38-word row stride
    __shared__ __align__(16) ush Ax[2][16][44];   // padded: 22-word row stride
    __shared__ int s_cnt;

    const bool xbf = probe_bf16((const ush*)X, tid, &s_cnt);

    {
        ush* p = &Ax[0][0][0];
        for (int i = tid; i < 2 * 16 * 44; i += 256) p[i] = 0;
    }
    __syncthreads();

    {
        const int tx0 = dir ? 71 : 0;
        if (tid < 144) {
            int r = tid / 9, k = tid - 9 * r;
            size_t idx = ((size_t)(gb0 + r) * 72 + tx0) * 9 + k;
            ush hv, lv;
            if (xbf) { hv = ((const ush*)X)[idx]; lv = 0; }
            else { float v = ((const float*)X)[idx]; hv = f2bf(v); lv = f2bf(v - bf2f(hv)); }
            Ax[0][r][2 * k]     = hv;
            Ax[0][r][2 * k + 1] = lv;
        }
    }

    short8 bU[3][2];
    short8 bW[3];
#pragma unroll
    for (int g = 0; g < 3; ++g) {
        const int col = g * 64 + u;
#pragma unroll
        for (int ks = 0; ks < 2; ++ks) {
            short8 f;
#pragma unroll
            for (int j = 0; j < 8; ++j) {
                int kp = ks * 32 + q * 8 + j;
                f[j] = (short)U[(size_t)kp * 192 + col];
            }
            bU[g][ks] = f;
        }
        short8 fw;
#pragma unroll
        for (int j = 0; j < 8; ++j) {
            int kp = q * 8 + j;
            fw[j] = (kp < 18) ? (short)W[(size_t)(kp >> 1) * 192 + col] : (short)0;
        }
        bW[g] = fw;
    }

    const float bz  = bf2f(bi[u])       + bf2f(br[u]);        // pre-scaled
    const float brg = bf2f(bi[64 + u])  + bf2f(br[64 + u]);   // pre-scaled
    const float bih = bf2f(bi[128 + u]);                      // unscaled (relu)
    const float brh = bf2f(br[128 + u]);
    const f32x4 Cz  = {bz,  bz,  bz,  bz};
    const f32x4 Cr  = {brg, brg, brg, brg};
    const f32x4 Chx = {bih, bih, bih, bih};
    const f32x4 Chr = {brh, brh, brh, brh};

    float hreg[4];
#pragma unroll
    for (int i = 0; i < 4; ++i) {
        int m = q * 4 + i;
        size_t idx = (size_t)(gb0 + m) * 64 + u;
        float hv = xbf ? bf2f(((const ush*)h0)[idx])
                       : ((const float*)h0)[idx];
        hreg[i] = hv;
        Ah[0][m][u] = f2bf(hv);
    }

    const int r2 = tid >> 3, c2 = tid & 7;
    const int r0x = tid / 9, k0x = tid - 9 * r0x;

    // depth-2 x pipeline, raw bits: craw holds x(t+1); conversion at the
    // LDS-write point one step later.
    unsigned int craw = 0;
    if (tid < 144) {
        const int tx = dir ? 70 : 1;
        size_t idx = ((size_t)(gb0 + r0x) * 72 + tx) * 9 + k0x;
        craw = xbf ? (unsigned int)((const ush*)X)[idx]
                   : ((const unsigned int*)X)[idx];
    }
    __syncthreads();

#pragma unroll 2
    for (int t = 0; t < 72; ++t) {
        const int cur = t & 1, nb = cur ^ 1;

        unsigned int fraw = 0;
        if (t < 70 && tid < 144) {
            const int tx = dir ? (69 - t) : (t + 2);
            size_t idx = ((size_t)(gb0 + r0x) * 72 + tx) * 9 + k0x;
            fraw = xbf ? (unsigned int)((const ush*)X)[idx]
                       : ((const unsigned int*)X)[idx];
        }

        if (t > 0 && tid < 128) {
            const int tw = dir ? (71 - (t - 1)) : (t - 1);
            int4 v = *(const int4*)&Ah[cur][r2][c2 * 8];
            *(int4*)(seq + ((size_t)tw * bchunk + lb0 + r2) * 128 + dir * 64 + c2 * 8) = v;
        }

        __builtin_amdgcn_s_setprio(1);           // serial chain: favored
        const ush* ap = &Ah[cur][ln][0];
        short8 a0 = *(const short8*)(ap + q * 8);
        short8 a1 = *(const short8*)(ap + 32 + q * 8);
        short8 ax = *(const short8*)(&Ax[cur][ln][q * 8]);
        f32x4 az  = MFMA_B16(ax, bW[0], Cz);
        az        = MFMA_B16(a0, bU[0][0], az);
        az        = MFMA_B16(a1, bU[0][1], az);
        f32x4 ar  = MFMA_B16(ax, bW[1], Cr);
        ar        = MFMA_B16(a0, bU[1][0], ar);
        ar        = MFMA_B16(a1, bU[1][1], ar);
        f32x4 ahx = MFMA_B16(ax, bW[2], Chx);
        f32x4 ahr = MFMA_B16(a0, bU[2][0], Chr);
        ahr       = MFMA_B16(a1, bU[2][1], ahr);

#pragma unroll
        for (int i = 0; i < 4; ++i) {
            const int m = q * 4 + i;
            float z = sigm_pre(az[i]);
            float r = sigm_pre(ar[i]);
            float pre = ahx[i] + r * ahr[i];
            float hh = fmaxf(pre, 0.0f);
            float hn = hh + z * (hreg[i] - hh);
            hreg[i] = hn;
            Ah[nb][m][u] = f2bf(hn);
        }
        __builtin_amdgcn_s_setprio(0);           // filler work: deferrable

        if (t < 71 && tid < 144) {
            ush hv, lv;
            if (xbf) { hv = (ush)craw; lv = 0; }
            else {
                float v = __uint_as_float(craw);
                hv = f2bf(v); lv = f2bf(v - bf2f(hv));
            }
            Ax[nb][r0x][2 * k0x]     = hv;
            Ax[nb][r0x][2 * k0x + 1] = lv;
        }
        craw = fraw;
        lds_barrier();
    }

    if (tid < 128) {
        const int tw = dir ? 0 : 71;
        int4 v = *(const int4*)&Ah[0][r2][c2 * 8];
        *(int4*)(seq + ((size_t)tw * bchunk + lb0 + r2) * 128 + dir * 64 + c2 * 8) = v;
    }
}

// ---------------------------------------------------------------------------
// Layer 2 (R7 structure, 81.4us measured): bidirectional GRU(64), tanh
// (pre-scaled). 4 waves x 16 units; per-lane seq A-frags direct from global
// with a period-3 zero-mov pipeline (named sets A/B/D: load at s, consume at
// s+3). Ah padded 72->76 (conflict-free). setprio(1) wraps the serial
// recurrence chain (T5); proj MFMAs + reload run at prio 0. One LDS-only
// barrier/step. grid (bchunk/16, 2), block 256.
// ---------------------------------------------------------------------------
#define G2STEP(T, S0, S1, S2, S3)                                              \
    do {                                                                       \
        const int cur_ = (T) & 1, nb_ = cur_ ^ 1;                              \
        __builtin_amdgcn_s_setprio(1);                                         \
        const ush* ap_ = &Ah[cur_][ln][0];                                     \
        short8 a0 = *(const short8*)(ap_ + q * 8);                             \
        short8 a1 = *(const short8*)(ap_ + 32 + q * 8);                        \
        f32x4 az  = MFMA_B16(a0, bU[0][0], P0);                                \
        az        = MFMA_B16(a1, bU[0][1], az);                                \
        f32x4 ar  = MFMA_B16(a0, bU[1][0], P1);                                \
        ar        = MFMA_B16(a1, bU[1][1], ar);                                \
        f32x4 ahr = MFMA_B16(a0, bU[2][0], Chr);                               \
        ahr       = MFMA_B16(a1, bU[2][1], ahr);                               \
        f32x4 ahx = P2;                                                        \
        _Pragma("unroll") for (int i = 0; i < 4; ++i) {                        \
            const int m = q * 4 + i;                                           \
            float z = sigm_pre(az[i]);                                         \
            float r = sigm_pre(ar[i]);                                         \
            float pre = ahx[i] + r * ahr[i];                                   \
            float hh = tanh_pre(pre);                                          \
            float hn = hh + z * (hreg[i] - hh);                                \
            hreg[i] = hn;                                                      \
            Ah[nb_][m][u] = f2bf(hn);                                          \
        }                                                                      \
        __builtin_amdgcn_s_setprio(0);                                         \
        if ((T) < 71) {         /* P <- proj(seq((T)+1)) from set regs */      \
            P0 = MFMA_B16(S0, bV[0][0], Cz);                                   \
            P0 = MFMA_B16(S1, bV[0][1], P0);                                   \
            P0 = MFMA_B16(S2, bV[0][2], P0);                                   \
            P0 = MFMA_B16(S3, bV[0][3], P0);                                   \
            P1 = MFMA_B16(S0, bV[1][0], Cr);                                   \
            P1 = MFMA_B16(S1, bV[1][1], P1);                                   \
            P1 = MFMA_B16(S2, bV[1][2], P1);                                   \
            P1 = MFMA_B16(S3, bV[1][3], P1);                                   \
            P2 = MFMA_B16(S0, bV[2][0], Chx);                                  \
            P2 = MFMA_B16(S1, bV[2][1], P2);                                   \
            P2 = MFMA_B16(S2, bV[2][2], P2);                                   \
            P2 = MFMA_B16(S3, bV[2][3], P2);                                   \
        }                                                                      \
        if ((T) <= 67) {        /* reload set with seq((T)+4) */               \
            const ush* sp_ = sptr0 + (long long)((T) + 4) * tstride;           \
            S0 = *(const short8*)(sp_);                                        \
            S1 = *(const short8*)(sp_ + 32);                                   \
            S2 = *(const short8*)(sp_ + 64);                                   \
            S3 = *(const short8*)(sp_ + 96);                                   \
        }                                                                      \
        lds_barrier();                                                         \
    } while (0)

__global__ __launch_bounds__(256, 1)
void gru2_kernel(const ush* __restrict__ seq, int cb, int bchunk,
                 const ush* __restrict__ W2f, const ush* __restrict__ U2f,
                 const ush* __restrict__ bi2f, const ush* __restrict__ br2f,
                 const ush* __restrict__ W2b, const ush* __restrict__ U2b,
                 const ush* __restrict__ bi2b, const ush* __restrict__ br2b,
                 float* __restrict__ feat)
{
    const int tid  = threadIdx.x;
    const int lane = tid & 63;
    const int wv   = tid >> 6;
    const int q    = lane >> 4;
    const int ln   = lane & 15;
    const int dir  = blockIdx.y;
    const int lb0  = blockIdx.x * 16;
    const int gb0  = cb + lb0;
    const int u    = wv * 16 + ln;

    const ush* W  = dir ? W2b  : W2f;
    const ush* U  = dir ? U2b  : U2f;
    const ush* bi = dir ? bi2b : bi2f;
    const ush* br = dir ? br2b : br2f;

    __shared__ __align__(16) ush Ah[2][16][76];   // padded row stride

    {
        ush* p = &Ah[0][0][0];
        for (int i = tid; i < 16 * 76; i += 256) p[i] = 0;
    }

    const long long tstride = (long long)bchunk * 128 * (dir ? -1 : 1);
    const ush* sptr0 = seq + ((size_t)(lb0 + ln)) * 128 + q * 8
                     + (dir ? 71ll * bchunk * 128 : 0);

    short8 bU[3][2];
    short8 bV[3][4];
#pragma unroll
    for (int g = 0; g < 3; ++g) {
        const int col = g * 64 + u;
#pragma unroll
        for (int ks = 0; ks < 2; ++ks) {
            short8 f;
#pragma unroll
            for (int j = 0; j < 8; ++j) {
                int kp = ks * 32 + q * 8 + j;
                f[j] = (short)U[(size_t)kp * 192 + col];
            }
            bU[g][ks] = f;
        }
#pragma unroll
        for (int ks = 0; ks < 4; ++ks) {
            short8 fv;
#pragma unroll
            for (int j = 0; j < 8; ++j) {
                int kp = ks * 32 + q * 8 + j;
                fv[j] = (short)W[(size_t)kp * 192 + col];
            }
            bV[g][ks] = fv;
        }
    }

    const float bz  = bf2f(bi[u])       + bf2f(br[u]);        // pre-scaled
    const float brg = bf2f(bi[64 + u])  + bf2f(br[64 + u]);   // pre-scaled
    const float bih = bf2f(bi[128 + u]);                      // pre-scaled (tanh)
    const float brh = bf2f(br[128 + u]);
    const f32x4 Cz  = {bz,  bz,  bz,  bz};
    const f32x4 Cr  = {brg, brg, brg, brg};
    const f32x4 Chx = {bih, bih, bih, bih};
    const f32x4 Chr = {brh, brh, brh, brh};

    float hreg[4];
#pragma unroll
    for (int i = 0; i < 4; ++i) hreg[i] = 0.0f;

    // P = proj(seq(0)); sets A/B/D = seq(1)/seq(2)/seq(3)
    f32x4 P0, P1, P2;
    {
        const ush* sp = sptr0;
        short8 s0 = *(const short8*)(sp);
        short8 s1 = *(const short8*)(sp + 32);
        short8 s2 = *(const short8*)(sp + 64);
        short8 s3 = *(const short8*)(sp + 96);
        P0 = MFMA_B16(s0, bV[0][0], Cz);
        P0 = MFMA_B16(s1, bV[0][1], P0);
        P0 = MFMA_B16(s2, bV[0][2], P0);
        P0 = MFMA_B16(s3, bV[0][3], P0);
        P1 = MFMA_B16(s0, bV[1][0], Cr);
        P1 = MFMA_B16(s1, bV[1][1], P1);
        P1 = MFMA_B16(s2, bV[1][2], P1);
        P1 = MFMA_B16(s3, bV[1][3], P1);
        P2 = MFMA_B16(s0, bV[2][0], Chx);
        P2 = MFMA_B16(s1, bV[2][1], P2);
        P2 = MFMA_B16(s2, bV[2][2], P2);
        P2 = MFMA_B16(s3, bV[2][3], P2);
    }
    short8 A0, A1, A2, A3, B0, B1, B2, B3, D0, D1, D2, D3;
    {
        const ush* sp = sptr0 + tstride;
        A0 = *(const short8*)(sp);        A1 = *(const short8*)(sp + 32);
        A2 = *(const short8*)(sp + 64);   A3 = *(const short8*)(sp + 96);
    }
    {
        const ush* sp = sptr0 + 2 * tstride;
        B0 = *(const short8*)(sp);        B1 = *(const short8*)(sp + 32);
        B2 = *(const short8*)(sp + 64);   B3 = *(const short8*)(sp + 96);
    }
    {
        const ush* sp = sptr0 + 3 * tstride;
        D0 = *(const short8*)(sp);        D1 = *(const short8*)(sp + 32);
        D2 = *(const short8*)(sp + 64);   D3 = *(const short8*)(sp + 96);
    }
    __syncthreads();

    for (int t = 0; t < 72; t += 3) {
        G2STEP(t,     A0, A1, A2, A3);
        G2STEP(t + 1, B0, B1, B2, B3);
        G2STEP(t + 2, D0, D1, D2, D3);
    }

#pragma unroll
    for (int i = 0; i < 4; ++i) {
        const int m = q * 4 + i;
        feat[(size_t)(gb0 + m) * 128 + dir * 64 + u] = hreg[i];
    }
}

// ---------------------------------------------------------------------------
__global__ __launch_bounds__(256, 1)
void head_kernel(const float* __restrict__ feat,
                 const ush* __restrict__ dW, const ush* __restrict__ db,
                 const ush* __restrict__ oW, const ush* __restrict__ ob,
                 float* __restrict__ out)
{
    const int tid = threadIdx.x;
    const int b0  = blockIdx.x * 16;

    __shared__ __align__(16) ush Wl[128][136];
    __shared__ __align__(16) float fs[16][128];
    __shared__ __align__(16) float hs[16][136];
    __shared__ __align__(16) float ls[16][32];

    for (int i = tid; i < 2048; i += 256) {
        const int k = i >> 4;
        const int c = (i & 15) * 8;
        *(int4*)&Wl[k][c] = *(const int4*)(dW + (size_t)k * 128 + c);
    }
    {
        const float4* src = (const float4*)(feat + (size_t)b0 * 128);
        float4* dst = (float4*)&fs[0][0];
        for (int i = tid; i < 512; i += 256) dst[i] = src[i];
    }
    __syncthreads();

    {
        const int row = tid >> 4;
        const int j0  = (tid & 15) * 8;
        float acc[8];
#pragma unroll
        for (int jj = 0; jj < 8; ++jj) acc[jj] = bf2f(db[j0 + jj]);
        for (int k = 0; k < 128; ++k) {
            float f = fs[row][k];
            short8 w = *(const short8*)&Wl[k][j0];
#pragma unroll
            for (int jj = 0; jj < 8; ++jj)
                acc[jj] += f * bf2f((ush)w[jj]);
        }
#pragma unroll
        for (int jj = 0; jj < 8; ++jj) hs[row][j0 + jj] = fmaxf(acc[jj], 0.0f);
    }
    __syncthreads();

    for (int e = tid; e < 16 * 24; e += 256) {
        const int row = e / 24, l = e - 24 * row;
        float acc = bf2f(ob[l]);
        for (int k = 0; k < 128; ++k)
            acc += hs[row][k] * bf2f(oW[(size_t)k * 24 + l]);
        ls[row][l] = acc;
    }
    __syncthreads();

    for (int e = tid; e < 16 * 24; e += 256) {
        const int row = e / 24, l = e - 24 * row;
        float mx = ls[row][0];
#pragma unroll
        for (int k = 1; k < 24; ++k) mx = fmaxf(mx, ls[row][k]);
        float s = 0.0f;
#pragma unroll
        for (int k = 0; k < 24; ++k) s += __expf(ls[row][k] - mx);
        float v = __expf(ls[row][l] - mx) * rcp_f(s);
        out[(size_t)(b0 + row) * 24 + l] = v;
    }
}

// ---------------------------------------------------------------------------
extern "C" void kernel_launch(void* const* d_in, const int* in_sizes, int n_in,
                              void* d_out, int out_size, void* d_ws, size_t ws_size,
                              hipStream_t stream) {
    (void)in_sizes; (void)n_in; (void)out_size;

    static const int wc[20] = {
        1728, 12288, 192, 192,     // d1f W,U,bi,br   (t 0..3)
        1728, 12288, 192, 192,     // d1b             (t 4..7)
        24576, 12288, 192, 192,    // d2f             (t 8..11)
        24576, 12288, 192, 192,    // d2b             (t 12..15)
        16384, 128,                // dense           (t 16,17)
        3072, 24                   // out             (t 18,19)
    };

    WArgs a;
    int off = 0;
    for (int t = 0; t < 20; ++t) {
        a.src[t] = d_in[t + 3];
        a.off[t] = off;
        off += wc[t];
    }
    a.off[20] = off;                         // 122,904 elements

    const unsigned long long arena_bytes = 245952ull;
    const unsigned long long feat_bytes  = 4096ull * 128ull * 4ull;
    const unsigned long long seq_full    = 72ull * 4096ull * 128ull * 2ull;
    const unsigned long long fixed       = arena_bytes + feat_bytes;

    int nc = 32;
    for (int c = 1; c <= 32; c *= 2) {
        if (fixed + seq_full / (unsigned long long)c <= (unsigned long long)ws_size) { nc = c; break; }
    }
    const int bchunk = 4096 / nc;

    ush* arena  = (ush*)d_ws;
    float* feat = (float*)((char*)d_ws + arena_bytes);
    ush* seq    = (ush*)((char*)d_ws + fixed);

    convert_w<<<128, 256, 0, stream>>>(a, arena, (const ush*)d_in[0]);

    const ush* d1fW = arena + a.off[0];
    const ush* d1fU = arena + a.off[1];
    const ush* d1fbi= arena + a.off[2];
    const ush* d1fbr= arena + a.off[3];
    const ush* d1bW = arena + a.off[4];
    const ush* d1bU = arena + a.off[5];
    const ush* d1bbi= arena + a.off[6];
    const ush* d1bbr= arena + a.off[7];
    const ush* d2fW = arena + a.off[8];
    const ush* d2fU = arena + a.off[9];
    const ush* d2fbi= arena + a.off[10];
    const ush* d2fbr= arena + a.off[11];
    const ush* d2bW = arena + a.off[12];
    const ush* d2bU = arena + a.off[13];
    const ush* d2bbi= arena + a.off[14];
    const ush* d2bbr= arena + a.off[15];
    const ush* dW   = arena + a.off[16];
    const ush* db   = arena + a.off[17];
    const ush* oW   = arena + a.off[18];
    const ush* ob   = arena + a.off[19];

    for (int c = 0; c < nc; ++c) {
        const int cb = c * bchunk;
        gru1_kernel<<<dim3(bchunk / 16, 2), 256, 0, stream>>>(
            d_in[0], d_in[1], d_in[2], cb, bchunk,
            d1fW, d1fU, d1fbi, d1fbr, d1bW, d1bU, d1bbi, d1bbr, seq);
        gru2_kernel<<<dim3(bchunk / 16, 2), 256, 0, stream>>>(
            seq, cb, bchunk,
            d2fW, d2fU, d2fbi, d2fbr, d2bW, d2bU, d2bbi, d2bbr, feat);
    }
    head_kernel<<<256, 256, 0, stream>>>(
        feat, dW, db, oW, ob, (float*)d_out);
}

// Round 10
// 235.905 us; speedup vs baseline: 1.0658x; 1.0541x over previous
//
#include <hip/hip_runtime.h>
#include <hip/hip_bf16.h>

typedef __attribute__((ext_vector_type(8))) short short8;
typedef __attribute__((ext_vector_type(4))) float f32x4;

#define MFMA_B16(a, b, c) __builtin_amdgcn_mfma_f32_16x16x32_bf16((a), (b), (c), 0, 0, 0)

__device__ __forceinline__ float bf2f(unsigned short u) {
    union { unsigned int i; float f; } v; v.i = ((unsigned int)u) << 16; return v.f;
}
__device__ __forceinline__ unsigned short f2bf(float f) {
    union { float f; unsigned int i; } v; v.f = f;
    unsigned int r = v.i + 0x7fffu + ((v.i >> 16) & 1u);
    return (unsigned short)(r >> 16);
}
// fast HW transcendentals (1 inst each). Gate scale constants are folded into
// the weights at convert time: z/r pre-acts arrive pre-multiplied by -log2(e),
// gru2 candidate pre-acts by 2*log2(e).
__device__ __forceinline__ float rcp_f(float x) { return __builtin_amdgcn_rcpf(x); }
__device__ __forceinline__ float sigm_pre(float x) {      // x = -log2(e)*(...)
    return rcp_f(1.0f + __builtin_amdgcn_exp2f(x));
}
__device__ __forceinline__ float tanh_pre(float x) {      // x = 2*log2(e)*(...)
    return 1.0f - 2.0f * rcp_f(__builtin_amdgcn_exp2f(x) + 1.0f);
}

// LDS-only barrier: __syncthreads() forces `s_waitcnt vmcnt(0) expcnt(0)
// lgkmcnt(0)` before s_barrier, draining the global prefetch/stores into every
// timestep. Cross-wave traffic in the GRU loops is LDS-only (Ah/Ax), so
// lgkmcnt(0) + raw s_barrier is sufficient; global loads/stores stay in
// flight across steps. Memory-clobber asm on both sides pins LDS ops.
__device__ __forceinline__ void lds_barrier() {
    asm volatile("s_waitcnt lgkmcnt(0)" ::: "memory");
    __builtin_amdgcn_s_barrier();
    asm volatile("" ::: "memory");
}

// probe 256 shorts: bf16 vs fp32 discrimination (deterministic per call)
__device__ __forceinline__ bool probe_bf16(const unsigned short* p, int tid, int* s_cnt) {
    if (tid == 0) *s_cnt = 0;
    __syncthreads();
    unsigned short s = p[tid & 255];
    int e = (s >> 7) & 0xFF;
    if (tid < 256 && e >= 117 && e <= 137) atomicAdd(s_cnt, 1);
    __syncthreads();
    return *s_cnt >= 200;
}

// ---------------------------------------------------------------------------
// Convert 20 weight/bias tensors (NOT x, NOT h0) to a bf16 arena with gate
// scale folding. Tensors 0..15 are GRU (last dim 192): cols 0..127 (z,r gates)
// scaled by -log2(e); cols 128..191 scaled by 2*log2(e) for d2 (tanh) tensors
// (8..15), by 1 for d1 (relu) tensors (0..7). Tensors 16..19 (head) unscaled.
// ---------------------------------------------------------------------------
struct WArgs {
    const void* src[20];
    int off[21];
};

__global__ __launch_bounds__(256)
void convert_w(WArgs a, unsigned short* __restrict__ arena,
               const unsigned short* __restrict__ probe)
{
    __shared__ int cnt;
    const bool bf = probe_bf16(probe, threadIdx.x, &cnt);
    const int total = a.off[20];
    for (int i = blockIdx.x * 256 + threadIdx.x; i < total; i += gridDim.x * 256) {
        int t = 0;
        while (t < 19 && i >= a.off[t + 1]) ++t;
        const int local = i - a.off[t];
        float v = bf ? bf2f(((const unsigned short*)a.src[t])[local])
                     : ((const float*)a.src[t])[local];
        if (t < 16) {
            const int col = local % 192;
            if (col < 128) v *= -1.4426950408889634f;
            else if (t >= 8) v *= 2.885390081777927f;
        }
        arena[i] = f2bf(v);
    }
}

// ---------------------------------------------------------------------------
// Layer 1: bidirectional GRU(64), relu candidate. 16 rows/block, h bf16 K=64,
// x hi/lo bf16 K=32 via LDS, depth-2 x prefetch (raw bits, conversion deferred
// one step). In-loop barriers are LDS-only (lds_barrier) so x loads and seq
// stores pipeline across timesteps. grid: (bchunk/16, 2), block 256.
// ---------------------------------------------------------------------------
__global__ __launch_bounds__(256, 1)
void gru1_kernel(const void* __restrict__ X, const void* __restrict__ h0f,
                 const void* __restrict__ h0b, int cb, int bchunk,
                 const unsigned short* __restrict__ Wf, const unsigned short* __restrict__ Uf,
                 const unsigned short* __restrict__ bif, const unsigned short* __restrict__ brf,
                 const unsigned short* __restrict__ Wb, const unsigned short* __restrict__ Ub,
                 const unsigned short* __restrict__ bib, const unsigned short* __restrict__ brb,
                 unsigned short* __restrict__ seq)
{
    const int tid  = threadIdx.x;
    const int lane = tid & 63;
    const int wv   = tid >> 6;
    const int q    = lane >> 4;
    const int ln   = lane & 15;
    const int dir  = blockIdx.y;
    const int lb0  = blockIdx.x * 16;
    const int gb0  = cb + lb0;
    const int u    = wv * 16 + ln;

    const unsigned short* W  = dir ? Wb  : Wf;
    const unsigned short* U  = dir ? Ub  : Uf;
    const unsigned short* bi = dir ? bib : bif;
    const unsigned short* br = dir ? brb : brf;
    const void* h0 = dir ? h0b : h0f;

    __shared__ __align__(16) unsigned short Ah[2][16][72];
    __shared__ __align__(16) unsigned short Ax[2][16][40];
    __shared__ int s_cnt;

    const bool xbf = probe_bf16((const unsigned short*)X, tid, &s_cnt);

    {
        unsigned short* p = &Ax[0][0][0];
        for (int i = tid; i < 2 * 16 * 40; i += 256) p[i] = 0;
    }
    __syncthreads();

    {
        const int tx0 = dir ? 71 : 0;
        if (tid < 144) {
            int r = tid / 9, k = tid - 9 * r;
            size_t idx = ((size_t)(gb0 + r) * 72 + tx0) * 9 + k;
            unsigned short hv, lv;
            if (xbf) { hv = ((const unsigned short*)X)[idx]; lv = 0; }
            else { float v = ((const float*)X)[idx]; hv = f2bf(v); lv = f2bf(v - bf2f(hv)); }
            Ax[0][r][2 * k]     = hv;
            Ax[0][r][2 * k + 1] = lv;
        }
    }

    short8 bU[3][2];
    short8 bW[3];
#pragma unroll
    for (int g = 0; g < 3; ++g) {
        const int col = g * 64 + u;
#pragma unroll
        for (int ks = 0; ks < 2; ++ks) {
            short8 f;
#pragma unroll
            for (int j = 0; j < 8; ++j) {
                int kp = ks * 32 + q * 8 + j;
                f[j] = (short)U[(size_t)kp * 192 + col];
            }
            bU[g][ks] = f;
        }
        short8 fw;
#pragma unroll
        for (int j = 0; j < 8; ++j) {
            int kp = q * 8 + j;
            fw[j] = (kp < 18) ? (short)W[(size_t)(kp >> 1) * 192 + col] : (short)0;
        }
        bW[g] = fw;
    }

    const float bz  = bf2f(bi[u])       + bf2f(br[u]);        // pre-scaled
    const float brg = bf2f(bi[64 + u])  + bf2f(br[64 + u]);   // pre-scaled
    const float bih = bf2f(bi[128 + u]);                      // unscaled (relu)
    const float brh = bf2f(br[128 + u]);
    const f32x4 Cz  = {bz,  bz,  bz,  bz};
    const f32x4 Cr  = {brg, brg, brg, brg};
    const f32x4 Chx = {bih, bih, bih, bih};
    const f32x4 Chr = {brh, brh, brh, brh};

    float hreg[4];
#pragma unroll
    for (int i = 0; i < 4; ++i) {
        int m = q * 4 + i;
        size_t idx = (size_t)(gb0 + m) * 64 + u;
        float hv = xbf ? bf2f(((const unsigned short*)h0)[idx])
                       : ((const float*)h0)[idx];
        hreg[i] = hv;
        Ah[0][m][u] = f2bf(hv);
    }

    const int r2 = tid >> 3, c2 = tid & 7;
    const int r0x = tid / 9, k0x = tid - 9 * r0x;

    // depth-2 x pipeline, raw bits: craw holds x(t+1); conversion to bf16
    // hi/lo happens at the LDS-write point one step later (full-step
    // load->use distance, latency hidden under compute).
    unsigned int craw = 0;
    if (tid < 144) {
        const int tx = dir ? 70 : 1;
        size_t idx = ((size_t)(gb0 + r0x) * 72 + tx) * 9 + k0x;
        craw = xbf ? (unsigned int)((const unsigned short*)X)[idx]
                   : ((const unsigned int*)X)[idx];
    }
    __syncthreads();

#pragma unroll 2
    for (int t = 0; t < 72; ++t) {
        const int cur = t & 1, nb = cur ^ 1;

        unsigned int fraw = 0;
        if (t < 70 && tid < 144) {
            const int tx = dir ? (69 - t) : (t + 2);
            size_t idx = ((size_t)(gb0 + r0x) * 72 + tx) * 9 + k0x;
            fraw = xbf ? (unsigned int)((const unsigned short*)X)[idx]
                       : ((const unsigned int*)X)[idx];
        }

        if (t > 0 && tid < 128) {
            const int tw = dir ? (71 - (t - 1)) : (t - 1);
            int4 v = *(const int4*)&Ah[cur][r2][c2 * 8];
            *(int4*)(seq + ((size_t)tw * bchunk + lb0 + r2) * 128 + dir * 64 + c2 * 8) = v;
        }

        const unsigned short* ap = &Ah[cur][ln][0];
        short8 a0 = *(const short8*)(ap + q * 8);
        short8 a1 = *(const short8*)(ap + 32 + q * 8);
        short8 ax = *(const short8*)(&Ax[cur][ln][q * 8]);
        f32x4 az  = MFMA_B16(ax, bW[0], Cz);
        az        = MFMA_B16(a0, bU[0][0], az);
        az        = MFMA_B16(a1, bU[0][1], az);
        f32x4 ar  = MFMA_B16(ax, bW[1], Cr);
        ar        = MFMA_B16(a0, bU[1][0], ar);
        ar        = MFMA_B16(a1, bU[1][1], ar);
        f32x4 ahx = MFMA_B16(ax, bW[2], Chx);
        f32x4 ahr = MFMA_B16(a0, bU[2][0], Chr);
        ahr       = MFMA_B16(a1, bU[2][1], ahr);

#pragma unroll
        for (int i = 0; i < 4; ++i) {
            const int m = q * 4 + i;
            float z = sigm_pre(az[i]);
            float r = sigm_pre(ar[i]);
            float pre = ahx[i] + r * ahr[i];
            float hh = fmaxf(pre, 0.0f);
            float hn = hh + z * (hreg[i] - hh);
            hreg[i] = hn;
            Ah[nb][m][u] = f2bf(hn);
        }

        if (t < 71 && tid < 144) {
            unsigned short hv, lv;
            if (xbf) { hv = (unsigned short)craw; lv = 0; }
            else {
                float v = __uint_as_float(craw);
                hv = f2bf(v); lv = f2bf(v - bf2f(hv));
            }
            Ax[nb][r0x][2 * k0x]     = hv;
            Ax[nb][r0x][2 * k0x + 1] = lv;
        }
        craw = fraw;
        lds_barrier();
    }

    if (tid < 128) {
        const int tw = dir ? 0 : 71;
        int4 v = *(const int4*)&Ah[0][r2][c2 * 8];
        *(int4*)(seq + ((size_t)tw * bchunk + lb0 + r2) * 128 + dir * 64 + c2 * 8) = v;
    }
}

// ---------------------------------------------------------------------------
// Layer 2: bidirectional GRU(64), tanh (pre-scaled candidate). Per-lane seq
// A-frags direct from global, depth-3 prefetch (issue at t, consume at t+2 so
// HBM latency spans two short steps); 12 projection MFMAs for t+1 computed
// from the c regs, 6 recurrent + gates post-barrier. In-loop barriers are
// LDS-only so the prefetch stream never drains. grid (bchunk/16, 2).
// ---------------------------------------------------------------------------
__global__ __launch_bounds__(256, 1)
void gru2_kernel(const unsigned short* __restrict__ seq, int cb, int bchunk,
                 const unsigned short* __restrict__ W2f, const unsigned short* __restrict__ U2f,
                 const unsigned short* __restrict__ bi2f, const unsigned short* __restrict__ br2f,
                 const unsigned short* __restrict__ W2b, const unsigned short* __restrict__ U2b,
                 const unsigned short* __restrict__ bi2b, const unsigned short* __restrict__ br2b,
                 float* __restrict__ feat)
{
    const int tid  = threadIdx.x;
    const int lane = tid & 63;
    const int wv   = tid >> 6;
    const int q    = lane >> 4;
    const int ln   = lane & 15;
    const int dir  = blockIdx.y;
    const int lb0  = blockIdx.x * 16;
    const int gb0  = cb + lb0;
    const int u    = wv * 16 + ln;

    const unsigned short* W  = dir ? W2b  : W2f;
    const unsigned short* U  = dir ? U2b  : U2f;
    const unsigned short* bi = dir ? bi2b : bi2f;
    const unsigned short* br = dir ? br2b : br2f;

    __shared__ __align__(16) unsigned short Ah[2][16][72];

    {
        unsigned short* p = &Ah[0][0][0];
        for (int i = tid; i < 16 * 72; i += 256) p[i] = 0;
    }

    const long long tstride = (long long)bchunk * 128 * (dir ? -1 : 1);
    const unsigned short* sptr0 = seq + ((size_t)(lb0 + ln)) * 128 + q * 8
                                + (dir ? 71ll * bchunk * 128 : 0);

    short8 bU[3][2];
    short8 bV[3][4];
#pragma unroll
    for (int g = 0; g < 3; ++g) {
        const int col = g * 64 + u;
#pragma unroll
        for (int ks = 0; ks < 2; ++ks) {
            short8 f;
#pragma unroll
            for (int j = 0; j < 8; ++j) {
                int kp = ks * 32 + q * 8 + j;
                f[j] = (short)U[(size_t)kp * 192 + col];
            }
            bU[g][ks] = f;
        }
#pragma unroll
        for (int ks = 0; ks < 4; ++ks) {
            short8 fv;
#pragma unroll
            for (int j = 0; j < 8; ++j) {
                int kp = ks * 32 + q * 8 + j;
                fv[j] = (short)W[(size_t)kp * 192 + col];
            }
            bV[g][ks] = fv;
        }
    }

    const float bz  = bf2f(bi[u])       + bf2f(br[u]);        // pre-scaled
    const float brg = bf2f(bi[64 + u])  + bf2f(br[64 + u]);   // pre-scaled
    const float bih = bf2f(bi[128 + u]);                      // pre-scaled (tanh)
    const float brh = bf2f(br[128 + u]);
    const f32x4 Cz  = {bz,  bz,  bz,  bz};
    const f32x4 Cr  = {brg, brg, brg, brg};
    const f32x4 Chx = {bih, bih, bih, bih};
    const f32x4 Chr = {brh, brh, brh, brh};

    float hreg[4];
#pragma unroll
    for (int i = 0; i < 4; ++i) hreg[i] = 0.0f;

    f32x4 P0, P1, P2;
    {
        const unsigned short* sp = sptr0;
        short8 s0 = *(const short8*)(sp);
        short8 s1 = *(const short8*)(sp + 32);
        short8 s2 = *(const short8*)(sp + 64);
        short8 s3 = *(const short8*)(sp + 96);
        P0 = MFMA_B16(s0, bV[0][0], Cz);
        P0 = MFMA_B16(s1, bV[0][1], P0);
        P0 = MFMA_B16(s2, bV[0][2], P0);
        P0 = MFMA_B16(s3, bV[0][3], P0);
        P1 = MFMA_B16(s0, bV[1][0], Cr);
        P1 = MFMA_B16(s1, bV[1][1], P1);
        P1 = MFMA_B16(s2, bV[1][2], P1);
        P1 = MFMA_B16(s3, bV[1][3], P1);
        P2 = MFMA_B16(s0, bV[2][0], Chx);
        P2 = MFMA_B16(s1, bV[2][1], P2);
        P2 = MFMA_B16(s2, bV[2][2], P2);
        P2 = MFMA_B16(s3, bV[2][3], P2);
    }
    // invariant at top of step t: c holds seq(t+1), g holds seq(t+2)
    short8 c0, c1, c2, c3, g0, g1, g2, g3;
    {
        const unsigned short* sp = sptr0 + tstride;
        c0 = *(const short8*)(sp);
        c1 = *(const short8*)(sp + 32);
        c2 = *(const short8*)(sp + 64);
        c3 = *(const short8*)(sp + 96);
    }
    {
        const unsigned short* sp = sptr0 + 2 * tstride;
        g0 = *(const short8*)(sp);
        g1 = *(const short8*)(sp + 32);
        g2 = *(const short8*)(sp + 64);
        g3 = *(const short8*)(sp + 96);
    }
    __syncthreads();

#pragma unroll 2
    for (int t = 0; t < 72; ++t) {
        const int cur = t & 1, nb = cur ^ 1;

        short8 f0 = g0, f1 = g1, f2 = g2, f3 = g3;
        if (t < 69) {
            const unsigned short* sp = sptr0 + (long long)(t + 3) * tstride;
            f0 = *(const short8*)(sp);
            f1 = *(const short8*)(sp + 32);
            f2 = *(const short8*)(sp + 64);
            f3 = *(const short8*)(sp + 96);
        }

        const unsigned short* ap = &Ah[cur][ln][0];
        short8 a0 = *(const short8*)(ap + q * 8);
        short8 a1 = *(const short8*)(ap + 32 + q * 8);
        f32x4 az  = MFMA_B16(a0, bU[0][0], P0);
        az        = MFMA_B16(a1, bU[0][1], az);
        f32x4 ar  = MFMA_B16(a0, bU[1][0], P1);
        ar        = MFMA_B16(a1, bU[1][1], ar);
        f32x4 ahr = MFMA_B16(a0, bU[2][0], Chr);
        ahr       = MFMA_B16(a1, bU[2][1], ahr);
        f32x4 ahx = P2;

#pragma unroll
        for (int i = 0; i < 4; ++i) {
            const int m = q * 4 + i;
            float z = sigm_pre(az[i]);
            float r = sigm_pre(ar[i]);
            float pre = ahx[i] + r * ahr[i];
            float hh = tanh_pre(pre);
            float hn = hh + z * (hreg[i] - hh);
            hreg[i] = hn;
            Ah[nb][m][u] = f2bf(hn);
        }

        if (t < 71) {
            P0 = MFMA_B16(c0, bV[0][0], Cz);
            P0 = MFMA_B16(c1, bV[0][1], P0);
            P0 = MFMA_B16(c2, bV[0][2], P0);
            P0 = MFMA_B16(c3, bV[0][3], P0);
            P1 = MFMA_B16(c0, bV[1][0], Cr);
            P1 = MFMA_B16(c1, bV[1][1], P1);
            P1 = MFMA_B16(c2, bV[1][2], P1);
            P1 = MFMA_B16(c3, bV[1][3], P1);
            P2 = MFMA_B16(c0, bV[2][0], Chx);
            P2 = MFMA_B16(c1, bV[2][1], P2);
            P2 = MFMA_B16(c2, bV[2][2], P2);
            P2 = MFMA_B16(c3, bV[2][3], P2);
        }
        c0 = g0; c1 = g1; c2 = g2; c3 = g3;
        g0 = f0; g1 = f1; g2 = f2; g3 = f3;
        lds_barrier();
    }

#pragma unroll
    for (int i = 0; i < 4; ++i) {
        const int m = q * 4 + i;
        feat[(size_t)(gb0 + m) * 128 + dir * 64 + u] = hreg[i];
    }
}

// ---------------------------------------------------------------------------
__global__ __launch_bounds__(256, 1)
void head_kernel(const float* __restrict__ feat,
                 const unsigned short* __restrict__ dW, const unsigned short* __restrict__ db,
                 const unsigned short* __restrict__ oW, const unsigned short* __restrict__ ob,
                 float* __restrict__ out)
{
    const int tid = threadIdx.x;
    const int b0  = blockIdx.x * 16;

    __shared__ __align__(16) unsigned short Wl[128][136];
    __shared__ __align__(16) float fs[16][128];
    __shared__ __align__(16) float hs[16][136];
    __shared__ __align__(16) float ls[16][32];

    for (int i = tid; i < 2048; i += 256) {
        const int k = i >> 4;
        const int c = (i & 15) * 8;
        *(int4*)&Wl[k][c] = *(const int4*)(dW + (size_t)k * 128 + c);
    }
    {
        const float4* src = (const float4*)(feat + (size_t)b0 * 128);
        float4* dst = (float4*)&fs[0][0];
        for (int i = tid; i < 512; i += 256) dst[i] = src[i];
    }
    __syncthreads();

    {
        const int row = tid >> 4;
        const int j0  = (tid & 15) * 8;
        float acc[8];
#pragma unroll
        for (int jj = 0; jj < 8; ++jj) acc[jj] = bf2f(db[j0 + jj]);
        for (int k = 0; k < 128; ++k) {
            float f = fs[row][k];
            short8 w = *(const short8*)&Wl[k][j0];
#pragma unroll
            for (int jj = 0; jj < 8; ++jj)
                acc[jj] += f * bf2f((unsigned short)w[jj]);
        }
#pragma unroll
        for (int jj = 0; jj < 8; ++jj) hs[row][j0 + jj] = fmaxf(acc[jj], 0.0f);
    }
    __syncthreads();

    for (int e = tid; e < 16 * 24; e += 256) {
        const int row = e / 24, l = e - 24 * row;
        float acc = bf2f(ob[l]);
        for (int k = 0; k < 128; ++k)
            acc += hs[row][k] * bf2f(oW[(size_t)k * 24 + l]);
        ls[row][l] = acc;
    }
    __syncthreads();

    for (int e = tid; e < 16 * 24; e += 256) {
        const int row = e / 24, l = e - 24 * row;
        float mx = ls[row][0];
#pragma unroll
        for (int k = 1; k < 24; ++k) mx = fmaxf(mx, ls[row][k]);
        float s = 0.0f;
#pragma unroll
        for (int k = 0; k < 24; ++k) s += __expf(ls[row][k] - mx);
        float v = __expf(ls[row][l] - mx) * rcp_f(s);
        out[(size_t)(b0 + row) * 24 + l] = v;
    }
}

// ---------------------------------------------------------------------------
extern "C" void kernel_launch(void* const* d_in, const int* in_sizes, int n_in,
                              void* d_out, int out_size, void* d_ws, size_t ws_size,
                              hipStream_t stream) {
    (void)in_sizes; (void)n_in; (void)out_size;

    // arena tensors: d_in[3..18] (GRU weights/biases), d_in[19..22] (head)
    static const int wc[20] = {
        1728, 12288, 192, 192,     // d1f W,U,bi,br   (t 0..3)
        1728, 12288, 192, 192,     // d1b             (t 4..7)
        24576, 12288, 192, 192,    // d2f             (t 8..11)
        24576, 12288, 192, 192,    // d2b             (t 12..15)
        16384, 128,                // dense           (t 16,17)
        3072, 24                   // out             (t 18,19)
    };

    WArgs a;
    int off = 0;
    for (int t = 0; t < 20; ++t) {
        a.src[t] = d_in[t + 3];
        a.off[t] = off;
        off += wc[t];
    }
    a.off[20] = off;                         // 122,904 elements

    const unsigned long long arena_bytes = 245952ull;  // 122,904*2 padded to 16
    const unsigned long long feat_bytes  = 4096ull * 128ull * 4ull;
    const unsigned long long seq_full    = 72ull * 4096ull * 128ull * 2ull;
    const unsigned long long fixed       = arena_bytes + feat_bytes;

    int nc = 32;
    for (int c = 1; c <= 32; c *= 2) {
        if (fixed + seq_full / (unsigned long long)c <= (unsigned long long)ws_size) { nc = c; break; }
    }
    const int bchunk = 4096 / nc;

    unsigned short* arena = (unsigned short*)d_ws;
    float* feat           = (float*)((char*)d_ws + arena_bytes);
    unsigned short* seq   = (unsigned short*)((char*)d_ws + fixed);

    convert_w<<<128, 256, 0, stream>>>(a, arena, (const unsigned short*)d_in[0]);

    const unsigned short* d1fW = arena + a.off[0];
    const unsigned short* d1fU = arena + a.off[1];
    const unsigned short* d1fbi= arena + a.off[2];
    const unsigned short* d1fbr= arena + a.off[3];
    const unsigned short* d1bW = arena + a.off[4];
    const unsigned short* d1bU = arena + a.off[5];
    const unsigned short* d1bbi= arena + a.off[6];
    const unsigned short* d1bbr= arena + a.off[7];
    const unsigned short* d2fW = arena + a.off[8];
    const unsigned short* d2fU = arena + a.off[9];
    const unsigned short* d2fbi= arena + a.off[10];
    const unsigned short* d2fbr= arena + a.off[11];
    const unsigned short* d2bW = arena + a.off[12];
    const unsigned short* d2bU = arena + a.off[13];
    const unsigned short* d2bbi= arena + a.off[14];
    const unsigned short* d2bbr= arena + a.off[15];
    const unsigned short* dW   = arena + a.off[16];
    const unsigned short* db   = arena + a.off[17];
    const unsigned short* oW   = arena + a.off[18];
    const unsigned short* ob   = arena + a.off[19];

    for (int c = 0; c < nc; ++c) {
        const int cb = c * bchunk;
        gru1_kernel<<<dim3(bchunk / 16, 2), 256, 0, stream>>>(
            d_in[0], d_in[1], d_in[2], cb, bchunk,
            d1fW, d1fU, d1fbi, d1fbr, d1bW, d1bU, d1bbi, d1bbr, seq);
        gru2_kernel<<<dim3(bchunk / 16, 2), 256, 0, stream>>>(
            seq, cb, bchunk,
            d2fW, d2fU, d2fbi, d2fbr, d2bW, d2bU, d2bbi, d2bbr, feat);
    }
    head_kernel<<<256, 256, 0, stream>>>(
        feat, dW, db, oW, ob, (float*)d_out);
}